// Round 1
// baseline (195.990 us; speedup 1.0000x reference)
//
#include <hip/hip_runtime.h>
#include <stdint.h>

#define OBS_LEN 12
#define KS 20
#define BB 2048
#define HD 128
#define MIDD 256
#define NCQ 2

using f32x4  = __attribute__((ext_vector_type(4))) float;
using bf16x8 = __attribute__((ext_vector_type(8))) short;

static __device__ __forceinline__ short f2bf(float f){
  return __builtin_bit_cast(short, (__bf16)f);   // RNE convert
}
static __device__ __forceinline__ float hsig(float x){
  return fminf(fmaxf(fmaf(x, 0.16666666666666666f, 0.5f), 0.f), 1.f);
}
static __device__ __forceinline__ float clip1(float x){
  return fminf(fmaxf(x, -1.f), 1.f);
}
static __device__ __forceinline__ f32x4 mm(bf16x8 a, bf16x8 b, f32x4 c){
  return __builtin_amdgcn_mfma_f32_16x16x32_bf16(a, b, c, 0, 0, 0);
}

__global__ __launch_bounds__(256, 1)
void CRMF_35296041239144_kernel(
    const float* __restrict__ obs,  const float* __restrict__ pred,
    const float* __restrict__ mw0,  const float* __restrict__ mb0,
    const float* __restrict__ mw1,  const float* __restrict__ mb1,
    const float* __restrict__ wih,  const float* __restrict__ whh,
    const float* __restrict__ bih,  const float* __restrict__ bhh,
    const float* __restrict__ oww,  const float* __restrict__ obb,
    float* __restrict__ outp)
{
  __shared__ __align__(16) uint16_t hbuf[2][32*HD];   // bf16 h, double buffered, swizzled
  __shared__ __align__(16) uint16_t abuf[32*MIDD];    // bf16 MLP activations, swizzled
  __shared__ float2 xbuf[OBS_LEN][32];                // shifted obs[:, :, :2]

  const int tid = threadIdx.x;
  const int w   = tid >> 6;        // wave id 0..3
  const int l   = tid & 63;
  const int p   = l >> 4;          // lane group 0..3
  const int ln  = l & 15;
  const int wofs = w * 32;         // this wave's hdim slice base
  const bool w3 = (w == 3);

  const int kk = blockIdx.x >> 6;          // sample index k
  const int b0 = (blockIdx.x & 63) * 32;   // batch base

  // ---- stage h0 (pred_lstm_hidden) as bf16 into hbuf[0], swizzled ----
  {
    const float* src = pred + ((size_t)(kk*BB + b0))*HD;
    #pragma unroll
    for (int it=0; it<4; ++it){
      int u = tid + it*256;                 // 0..1023 covers 32x128 in float4s
      int row = u >> 5;
      int c4  = (u & 31) * 4;
      float4 v = *reinterpret_cast<const float4*>(src + row*HD + c4);
      int e = (row*HD + c4) ^ ((row&7)*8);
      uint32_t lo = (uint32_t)(uint16_t)f2bf(v.x) | ((uint32_t)(uint16_t)f2bf(v.y) << 16);
      uint32_t hi = (uint32_t)(uint16_t)f2bf(v.z) | ((uint32_t)(uint16_t)f2bf(v.w) << 16);
      *reinterpret_cast<uint32_t*>(&hbuf[0][e])   = lo;
      *reinterpret_cast<uint32_t*>(&hbuf[0][e+2]) = hi;
    }
  }
  // ---- stage shifted obs: xbuf[t] = obs[max(t-1,0)][b][:2] ----
  for (int u = tid; u < OBS_LEN*32; u += 256){
    int t = u >> 5, cc = u & 31;
    int st = t ? (t-1) : 0;
    const float* pp = obs + ((size_t)st*BB + b0 + cc)*3;
    xbuf[t][cc] = make_float2(pp[0], pp[1]);
  }

  // ---- recurrent weights -> registers (B-fragments, k = q*32 + p*8 + j) ----
  bf16x8 wfrag[8][4];
  float wihA[8], wihB[8], biasv[8];
  #pragma unroll
  for (int ct=0; ct<8; ++ct){
    int col = (ct>>1)*128 + wofs + (ct&1)*16 + ln;   // gate*128 + hdim
    wihA[ct]  = wih[col*2];
    wihB[ct]  = wih[col*2+1];
    biasv[ct] = bih[col] + bhh[col];
    #pragma unroll
    for (int q=0; q<4; ++q){
      const float* s = whh + col*HD + q*32 + p*8;
      float4 f0 = *reinterpret_cast<const float4*>(s);
      float4 f1 = *reinterpret_cast<const float4*>(s+4);
      bf16x8 wf;
      wf[0]=f2bf(f0.x); wf[1]=f2bf(f0.y); wf[2]=f2bf(f0.z); wf[3]=f2bf(f0.w);
      wf[4]=f2bf(f1.x); wf[5]=f2bf(f1.y); wf[6]=f2bf(f1.z); wf[7]=f2bf(f1.w);
      wfrag[ct][q] = wf;
    }
  }
  // wave 3 extra: out_w as a 9th column tile (only n<2 valid)
  bf16x8 wfragO[4];
  float ob = 0.f;
  if (w3){
    #pragma unroll
    for (int q=0; q<4; ++q){
      bf16x8 wf;
      #pragma unroll
      for (int j=0; j<8; ++j){
        int k = q*32 + p*8 + j;
        wf[j] = (ln < NCQ) ? f2bf(oww[k*NCQ + ln]) : (short)0;
      }
      wfragO[q] = wf;
    }
    if (ln < NCQ) ob = obb[ln];
  }

  __syncthreads();

  // ---- MLP GEMM1: [32,128] @ map_w0 -> [32,256], leaky_relu ----
  f32x4 acc1[2][4];
  #pragma unroll
  for (int ct=0; ct<4; ++ct){
    float mb = mb0[wofs*2 + ct*16 + ln];
    f32x4 v = {mb, mb, mb, mb};
    acc1[0][ct] = v; acc1[1][ct] = v;
  }
  #pragma unroll
  for (int q=0; q<4; ++q){
    bf16x8 af0 = *reinterpret_cast<const bf16x8*>(&hbuf[0][((ln   )*HD + q*32 + p*8) ^ ((ln&7)*8)]);
    bf16x8 af1 = *reinterpret_cast<const bf16x8*>(&hbuf[0][((16+ln)*HD + q*32 + p*8) ^ ((ln&7)*8)]);
    #pragma unroll
    for (int ct=0; ct<4; ++ct){
      bf16x8 wf;
      #pragma unroll
      for (int j=0; j<8; ++j)
        wf[j] = f2bf(mw0[(q*32 + p*8 + j)*MIDD + (wofs*2 + ct*16 + ln)]);
      acc1[0][ct] = mm(af0, wf, acc1[0][ct]);
      acc1[1][ct] = mm(af1, wf, acc1[1][ct]);
    }
  }
  #pragma unroll
  for (int rt=0; rt<2; ++rt)
  #pragma unroll
  for (int ct=0; ct<4; ++ct)
  #pragma unroll
  for (int r=0; r<4; ++r){
    float v = acc1[rt][ct][r];
    v = (v > 0.f) ? v : 0.01f*v;
    int row = rt*16 + p*4 + r;
    abuf[(row*MIDD + wofs*2 + ct*16 + ln) ^ ((row&7)*8)] = (uint16_t)f2bf(v);
  }
  __syncthreads();

  // ---- MLP GEMM2: [32,256] @ map_w1 -> h_init [32,128] ----
  f32x4 acc2[2][2];
  #pragma unroll
  for (int d=0; d<2; ++d){
    float mb = mb1[wofs + d*16 + ln];
    f32x4 v = {mb, mb, mb, mb};
    acc2[0][d] = v; acc2[1][d] = v;
  }
  #pragma unroll
  for (int q=0; q<8; ++q){
    bf16x8 af0 = *reinterpret_cast<const bf16x8*>(&abuf[((ln   )*MIDD + q*32 + p*8) ^ ((ln&7)*8)]);
    bf16x8 af1 = *reinterpret_cast<const bf16x8*>(&abuf[((16+ln)*MIDD + q*32 + p*8) ^ ((ln&7)*8)]);
    #pragma unroll
    for (int d=0; d<2; ++d){
      bf16x8 wf;
      #pragma unroll
      for (int j=0; j<8; ++j)
        wf[j] = f2bf(mw1[(q*32 + p*8 + j)*HD + (wofs + d*16 + ln)]);
      acc2[0][d] = mm(af0, wf, acc2[0][d]);
      acc2[1][d] = mm(af1, wf, acc2[1][d]);
    }
  }
  float c_[2][2][4];
  #pragma unroll
  for (int rt=0; rt<2; ++rt)
  #pragma unroll
  for (int d=0; d<2; ++d)
  #pragma unroll
  for (int r=0; r<4; ++r){
    int row = rt*16 + p*4 + r;
    hbuf[0][(row*HD + wofs + d*16 + ln) ^ ((row&7)*8)] = (uint16_t)f2bf(acc2[rt][d][r]);
    c_[rt][d][r] = 0.f;
  }
  __syncthreads();

  // ---- 12 recurrent steps ----
  f32x4 acc[2][8];
  f32x4 acc8[2];
  for (int t=0; t<OBS_LEN; ++t){
    const int cur = t & 1, nxt = cur ^ 1;
    // C-init = x@w_ih^T + (b_ih+b_hh), computed directly in D-layout
    #pragma unroll
    for (int rt=0; rt<2; ++rt){
      float2 xv[4];
      #pragma unroll
      for (int r=0; r<4; ++r) xv[r] = xbuf[t][rt*16 + p*4 + r];
      #pragma unroll
      for (int ct=0; ct<8; ++ct){
        f32x4 a;
        #pragma unroll
        for (int r=0; r<4; ++r)
          a[r] = fmaf(xv[r].x, wihA[ct], fmaf(xv[r].y, wihB[ct], biasv[ct]));
        acc[rt][ct] = a;
      }
    }
    if (w3){ f32x4 v = {ob,ob,ob,ob}; acc8[0] = v; acc8[1] = v; }
    // gates = C + h_prev @ w_hh^T   (wave3 also: out_{t-1} = h_prev @ out_w + out_b)
    #pragma unroll
    for (int q=0; q<4; ++q){
      bf16x8 af0 = *reinterpret_cast<const bf16x8*>(&hbuf[cur][((ln   )*HD + q*32 + p*8) ^ ((ln&7)*8)]);
      bf16x8 af1 = *reinterpret_cast<const bf16x8*>(&hbuf[cur][((16+ln)*HD + q*32 + p*8) ^ ((ln&7)*8)]);
      #pragma unroll
      for (int ct=0; ct<8; ++ct){
        acc[0][ct] = mm(af0, wfrag[ct][q], acc[0][ct]);
        acc[1][ct] = mm(af1, wfrag[ct][q], acc[1][ct]);
      }
      if (w3){
        acc8[0] = mm(af0, wfragO[q], acc8[0]);
        acc8[1] = mm(af1, wfragO[q], acc8[1]);
      }
    }
    if (w3 && t > 0 && ln < NCQ){
      #pragma unroll
      for (int rt=0; rt<2; ++rt)
      #pragma unroll
      for (int r=0; r<4; ++r){
        int cell = rt*16 + p*4 + r;
        outp[(((size_t)(t-1)*KS + kk)*BB + b0 + cell)*NCQ + ln] = acc8[rt][r];
      }
    }
    // gate math in fp32, c kept in registers, h_new -> bf16 -> hbuf[nxt]
    #pragma unroll
    for (int rt=0; rt<2; ++rt)
    #pragma unroll
    for (int d=0; d<2; ++d)
    #pragma unroll
    for (int r=0; r<4; ++r){
      float iv = hsig(acc[rt][0+d][r]);
      float fv = hsig(acc[rt][2+d][r]);
      float gv = clip1(acc[rt][4+d][r]);
      float ov = hsig(acc[rt][6+d][r]);
      float cv = fmaf(fv, c_[rt][d][r], iv*gv);
      c_[rt][d][r] = cv;
      float hv = ov * clip1(cv);
      int row = rt*16 + p*4 + r;
      hbuf[nxt][(row*HD + wofs + d*16 + ln) ^ ((row&7)*8)] = (uint16_t)f2bf(hv);
    }
    __syncthreads();
  }

  // ---- final output out_11 = h_11 @ out_w + out_b  (h_11 is in hbuf[0]) ----
  if (w3){
    f32x4 o0 = {ob,ob,ob,ob}; f32x4 o1 = o0;
    #pragma unroll
    for (int q=0; q<4; ++q){
      bf16x8 af0 = *reinterpret_cast<const bf16x8*>(&hbuf[0][((ln   )*HD + q*32 + p*8) ^ ((ln&7)*8)]);
      bf16x8 af1 = *reinterpret_cast<const bf16x8*>(&hbuf[0][((16+ln)*HD + q*32 + p*8) ^ ((ln&7)*8)]);
      o0 = mm(af0, wfragO[q], o0);
      o1 = mm(af1, wfragO[q], o1);
    }
    if (ln < NCQ){
      #pragma unroll
      for (int r=0; r<4; ++r){
        outp[(((size_t)11*KS + kk)*BB + b0 +      (p*4 + r))*NCQ + ln] = o0[r];
        outp[(((size_t)11*KS + kk)*BB + b0 + 16 + (p*4 + r))*NCQ + ln] = o1[r];
      }
    }
  }
}

extern "C" void kernel_launch(void* const* d_in, const int* in_sizes, int n_in,
                              void* d_out, int out_size, void* d_ws, size_t ws_size,
                              hipStream_t stream) {
  (void)in_sizes; (void)n_in; (void)d_ws; (void)ws_size; (void)out_size;
  CRMF_35296041239144_kernel<<<dim3(1280), dim3(256), 0, stream>>>(
      (const float*)d_in[0], (const float*)d_in[1], (const float*)d_in[2],
      (const float*)d_in[3], (const float*)d_in[4], (const float*)d_in[5],
      (const float*)d_in[6], (const float*)d_in[7], (const float*)d_in[8],
      (const float*)d_in[9], (const float*)d_in[10], (const float*)d_in[11],
      (float*)d_out);
}